// Round 19
// baseline (84.385 us; speedup 1.0000x reference)
//
#include <hip/hip_runtime.h>
#include <math.h>

#define DD 128
#define NSLICE 48
#define SLICE 11
#define NBINS 512
#define SHIFT 10.0f
#define L2E_T 14.4269504089f   // 10 * log2(e)

#define AS1 __attribute__((address_space(1)))
#define AS3 __attribute__((address_space(3)))

typedef _Float16 f16x8 __attribute__((ext_vector_type(8)));
typedef _Float16 f16x2 __attribute__((ext_vector_type(2)));
typedef float f32x4 __attribute__((ext_vector_type(4)));

// guard-free 2^x: args are in [-29, 0]
__device__ __forceinline__ float ex2(float x) {
#if __has_builtin(__builtin_amdgcn_exp2f)
    return __builtin_amdgcn_exp2f(x);
#else
    return exp2f(x);
#endif
}

// ---- parallel zero: row partials (3MB) + hist + d_out; 768 blocks ----
__global__ __launch_bounds__(256)
void zero_kernel(float4* __restrict__ ep4, int n4, int* __restrict__ hist,
                 float* __restrict__ out)
{
    int g = blockIdx.x * 256 + threadIdx.x;
    if (g < n4) ep4[g] = make_float4(0.f, 0.f, 0.f, 0.f);
    if (g < NBINS / 4) reinterpret_cast<int4*>(hist)[g] = make_int4(0, 0, 0, 0);
    if (g == 0) out[0] = 0.f;
}

// ---- normalize rows -> f16, labels, histogram ----
__global__ __launch_bounds__(256)
void norm_kernel(const float* __restrict__ f, const int* __restrict__ labels,
                 _Float16* __restrict__ fh, int* __restrict__ labm,
                 int* __restrict__ hist, int M, int nrep)
{
    int gw = (blockIdx.x * 256 + threadIdx.x) >> 6;   // one wave per row
    int lane = threadIdx.x & 63;
    if (gw >= M) return;
    float2 v = *reinterpret_cast<const float2*>(&f[(size_t)gw * DD + lane * 2]);
    float ss = v.x * v.x + v.y * v.y;
    #pragma unroll
    for (int m = 1; m < 64; m <<= 1) ss += __shfl_xor(ss, m);
    float inv = 1.0f / fmaxf(sqrtf(ss), 1e-12f);
    f16x2 h; h[0] = (_Float16)(v.x * inv); h[1] = (_Float16)(v.y * inv);
    *reinterpret_cast<f16x2*>(&fh[(size_t)gw * DD + lane * 2]) = h;
    if (lane == 0) {
        int lb = labels[gw / nrep];
        labm[gw] = lb;
        if ((gw % nrep) == 0) atomicAdd(&hist[lb], nrep);
    }
}

// ---- main: SYMMETRY-HALVED f16 MFMA (each unordered pair computed once) ----
// Per i-block bx: 16 diagonal subtiles full (row-sums only -> covers all
// within-block ordered pairs once); upper subtiles s >= (bx+1)*16 computed
// once, row-sums -> E_i AND column-sums -> E_j (16-lane shfl reduce, plain
// stores to slot bx*4+w -- written exactly once per j, no atomics, no zero
// needed for the range final reads). Load balance: block x = pair
// {bx, 31-bx}, whose concatenated subtile list is ALWAYS 528 long; 48
// slices of 11 -> 768 uniform blocks (3/CU, 1 round, 11 subtiles each vs
// R17's 21.3). Compute core/LDS-DMA staging/paired phases = R17 (proven
// clean at ~140 regs; col adds ~8 transient).
__global__ __launch_bounds__(256, 3)
void supcon_main(const _Float16* __restrict__ fh, const int* __restrict__ labm,
                 float* __restrict__ EpE, float* __restrict__ EpP,
                 float* __restrict__ EcE, float* __restrict__ EcP, int M)
{
    __shared__ float4 jbuf[2][1024];   // 2 x (64 rows x 16 chunks of 16B)

    const int tid = threadIdx.x;
    const int lane = tid & 63;
    const int w = tid >> 6;
    const int rowsel = lane & 15;
    const int grp = lane >> 4;
    const int ksel = grp * 8;
    const int rowlim = M - 1;

    const int pid = blockIdx.x;        // 0..15: pairs bx=pid and 31-pid
    const int by = blockIdx.y;         // 0..47 slice
    const int NS = M / 16;             // 512 subtiles total
    const int LA = NS - 16 * pid;      // segment-A length (bx = pid)

    // staging geometry (thread-constant): wave w, instr q covers LDS slots
    // [(q*4+w)*64, +64); slot s holds global chunk (row s>>4, c (s&15)^((s>>4)&7))
    int srow[4], scol[4];
    #pragma unroll
    for (int q = 0; q < 4; ++q) {
        int s = (q * 4 + w) * 64 + lane;
        srow[q] = s >> 4;
        scol[q] = ((s & 15) ^ ((s >> 4) & 7)) * 8;
    }

#define STAGE(bb, rbase) { \
    _Pragma("unroll") for (int q = 0; q < 4; ++q) { \
        int rr = (rbase) + srow[q]; if (rr > rowlim) rr = rowlim; \
        const _Float16* gsrc = fh + (size_t)rr * DD + scol[q]; \
        __builtin_amdgcn_global_load_lds((const AS1 void*)gsrc, \
            (AS3 void*)&jbuf[bb][(q * 4 + w) * 64], 16, 0, 0); } }

#define LDSAF(bb, k) { \
    _Pragma("unroll") for (int kk = 0; kk < 4; ++kk) { \
        int slot = ((k) * 16 + rowsel) * 16 + ((kk * 4 + grp) ^ (rowsel & 7)); \
        af[kk] = *reinterpret_cast<const f16x8*>(&jbuf[bb][slot]); } }

#define MFMA16(A, c0, c1, c2, c3) { \
    _Pragma("unroll") for (int kk = 0; kk < 4; ++kk) { \
        c0 = __builtin_amdgcn_mfma_f32_16x16x32_f16(A[kk], bfr[0][kk], c0, 0, 0, 0); \
        c1 = __builtin_amdgcn_mfma_f32_16x16x32_f16(A[kk], bfr[1][kk], c1, 0, 0, 0); \
        c2 = __builtin_amdgcn_mfma_f32_16x16x32_f16(A[kk], bfr[2][kk], c2, 0, 0, 0); \
        c3 = __builtin_amdgcn_mfma_f32_16x16x32_f16(A[kk], bfr[3][kk], c3, 0, 0, 0); } }

#define RED4(v) { v += __shfl_xor(v, 1); v += __shfl_xor(v, 2); \
                  v += __shfl_xor(v, 4); v += __shfl_xor(v, 8); }

#define EPI1C(t, cc, L) { \
    float e0 = ex2(__builtin_fmaf(cc[0], L2E_T, -L2E_T)); \
    float e1 = ex2(__builtin_fmaf(cc[1], L2E_T, -L2E_T)); \
    float e2 = ex2(__builtin_fmaf(cc[2], L2E_T, -L2E_T)); \
    float e3 = ex2(__builtin_fmaf(cc[3], L2E_T, -L2E_T)); \
    esum[t] += (e0 + e1) + (e2 + e3); \
    float q0 = (L.x == li[t]) ? cc[0] : 0.f; \
    float q1 = (L.y == li[t]) ? cc[1] : 0.f; \
    float q2 = (L.z == li[t]) ? cc[2] : 0.f; \
    float q3 = (L.w == li[t]) ? cc[3] : 0.f; \
    psum[t] += (q0 + q1) + (q2 + q3); \
    cE0 += e0; cE1 += e1; cE2 += e2; cE3 += e3; \
    cP0 += q0; cP1 += q1; cP2 += q2; cP3 += q3; }

// epilogue for one subtile sg: row sums always; col sums iff upper tile
#define EPICOL(c0v, c1v, c2v, c3v, sg) { \
    const int4 lj = *reinterpret_cast<const int4*>(&labm[(sg) * 16 + grp * 4]); \
    const bool doc = (((sg) >> 4) != BXr); \
    float cE0 = 0.f, cE1 = 0.f, cE2 = 0.f, cE3 = 0.f; \
    float cP0 = 0.f, cP1 = 0.f, cP2 = 0.f, cP3 = 0.f; \
    EPI1C(0, c0v, lj); EPI1C(1, c1v, lj); EPI1C(2, c2v, lj); EPI1C(3, c3v, lj); \
    if (doc) { \
        RED4(cE0); RED4(cE1); RED4(cE2); RED4(cE3); \
        RED4(cP0); RED4(cP1); RED4(cP2); RED4(cP3); \
        if (rowsel == 0) { \
            float4 vE; vE.x = cE0; vE.y = cE1; vE.z = cE2; vE.w = cE3; \
            float4 vP; vP.x = cP0; vP.y = cP1; vP.z = cP2; vP.w = cP3; \
            size_t co = (size_t)(BXr * 4 + w) * M + (sg) * 16 + grp * 4; \
            *reinterpret_cast<float4*>(&EcE[co]) = vE; \
            *reinterpret_cast<float4*>(&EcP[co]) = vP; } } }

#define PAIRC(bb, k0, k1, sg0, sg1) { \
    f16x8 af[4]; \
    LDSAF(bb, k0); \
    f32x4 A0 = {0,0,0,0}, A1 = {0,0,0,0}, A2 = {0,0,0,0}, A3 = {0,0,0,0}; \
    MFMA16(af, A0, A1, A2, A3); \
    LDSAF(bb, k1); \
    f32x4 B0 = {0,0,0,0}, B1 = {0,0,0,0}, B2 = {0,0,0,0}, B3 = {0,0,0,0}; \
    MFMA16(af, B0, B1, B2, B3); \
    EPICOL(A0, A1, A2, A3, (sg0)); \
    EPICOL(B0, B1, B2, B3, (sg1)); }

#define SINGLEC(bb, k0, sg0) { \
    f16x8 af[4]; \
    LDSAF(bb, k0); \
    f32x4 A0 = {0,0,0,0}, A1 = {0,0,0,0}, A2 = {0,0,0,0}, A3 = {0,0,0,0}; \
    MFMA16(af, A0, A1, A2, A3); \
    EPICOL(A0, A1, A2, A3, (sg0)); }

// process N_ subtiles starting at S0_ for i-block BX_; flush row partials
#define DO_RUN(BX_, S0_, N_) { \
    const int BXr = (BX_); \
    const int S0r = (S0_); \
    const int Nr = (N_); \
    const int ibase = BXr * 256 + w * 64; \
    f16x8 bfr[4][4]; \
    _Pragma("unroll") for (int t = 0; t < 4; ++t) \
        _Pragma("unroll") for (int kk = 0; kk < 4; ++kk) \
            bfr[t][kk] = *reinterpret_cast<const f16x8*>( \
                &fh[(size_t)(ibase + t * 16 + rowsel) * DD + kk * 32 + ksel]); \
    int li[4]; \
    _Pragma("unroll") for (int t = 0; t < 4; ++t) \
        li[t] = labm[ibase + t * 16 + rowsel]; \
    float esum[4] = {0.f, 0.f, 0.f, 0.f}; \
    float psum[4] = {0.f, 0.f, 0.f, 0.f}; \
    const int nb = (Nr + 3) >> 2; \
    STAGE(0, S0r * 16); \
    __syncthreads(); \
    for (int t = 0; t < nb; ++t) { \
        if (t + 1 < nb) STAGE((t + 1) & 1, (S0r + (t + 1) * 4) * 16); \
        const int nv = (t == nb - 1) ? (Nr - (nb - 1) * 4) : 4; \
        const int sgb = S0r + t * 4; \
        if (nv >= 2) PAIRC(t & 1, 0, 1, sgb, sgb + 1); \
        if (nv == 4) { PAIRC(t & 1, 2, 3, sgb + 2, sgb + 3); } \
        else if (nv == 3) { SINGLEC(t & 1, 2, sgb + 2); } \
        else if (nv == 1) { SINGLEC(t & 1, 0, sgb); } \
        __syncthreads(); \
    } \
    _Pragma("unroll") for (int t = 0; t < 4; ++t) { \
        float e = esum[t], pp = psum[t]; \
        e += __shfl_xor(e, 16); e += __shfl_xor(e, 32); \
        pp += __shfl_xor(pp, 16); pp += __shfl_xor(pp, 32); \
        if (lane < 16) { \
            size_t o = (size_t)by * M + ibase + t * 16 + lane; \
            EpE[o] = e; \
            EpP[o] = pp; } } }

    // slice [u0,u1) of the 528-long concatenated list {bx=pid} ++ {bx=31-pid}
    const int u0 = by * SLICE, u1 = u0 + SLICE;
    int a0 = u0, a1 = (u1 < LA) ? u1 : LA;
    if (a1 > a0) DO_RUN(pid, pid * 16 + a0, a1 - a0);
    int b0 = (u0 > LA) ? u0 : LA, b1 = u1;
    if (b1 > b0) DO_RUN(31 - pid, (31 - pid) * 16 + (b0 - LA), b1 - b0);

#undef STAGE
#undef LDSAF
#undef MFMA16
#undef RED4
#undef EPI1C
#undef EPICOL
#undef PAIRC
#undef SINGLEC
#undef DO_RUN
}

// ---- per-row loss: 48 row partials + 4*(i>>8) col partials, exact self ----
__global__ __launch_bounds__(256)
void final_fused(const _Float16* __restrict__ fh, const float* __restrict__ EpE,
                 const float* __restrict__ EpP, const float* __restrict__ EcE,
                 const float* __restrict__ EcP, const int* __restrict__ labm,
                 const int* __restrict__ hist, float* __restrict__ out, int M)
{
    __shared__ float red[4];
    const int b = blockIdx.x;                       // = i >> 8
    const int i = b * 256 + threadIdx.x;
    float aii = 0.f;
    const f16x8* fr = reinterpret_cast<const f16x8*>(&fh[(size_t)i * DD]);
    #pragma unroll
    for (int k = 0; k < 16; ++k) {
        f16x8 hv = fr[k];
        #pragma unroll
        for (int e = 0; e < 8; ++e) {
            float x = (float)hv[e];
            aii = __builtin_fmaf(x, x, aii);
        }
    }
    float E = 0.f, P = 0.f;
    #pragma unroll
    for (int k = 0; k < NSLICE; ++k) {
        E += EpE[(size_t)k * M + i];
        P += EpP[(size_t)k * M + i];
    }
    const int nc = 4 * b;                           // col slots bx<b, 4 waves
    for (int k = 0; k < nc; ++k) {
        E += EcE[(size_t)k * M + i];
        P += EcP[(size_t)k * M + i];
    }
    int lb = labm[i];
    float cnt = (float)(hist[lb] - 1);
    E -= ex2(__builtin_fmaf(aii, L2E_T, -L2E_T));   // drop self exp
    float term = (SHIFT + logf(E)) - SHIFT * (P - aii) / cnt;

    #pragma unroll
    for (int m = 1; m < 64; m <<= 1) term += __shfl_xor(term, m);
    int lane = threadIdx.x & 63, wv = threadIdx.x >> 6;
    if (lane == 0) red[wv] = term;
    __syncthreads();
    if (threadIdx.x == 0)
        atomicAdd(out, (red[0] + red[1] + red[2] + red[3]) / (float)M);
}

extern "C" void kernel_launch(void* const* d_in, const int* in_sizes, int n_in,
                              void* d_out, int out_size, void* d_ws, size_t ws_size,
                              hipStream_t stream)
{
    const float* feats = (const float*)d_in[0];
    const int* labels = (const int*)d_in[1];
    const int Bn = in_sizes[1];
    const int M = in_sizes[0] / DD;    // 8192
    const int nrep = M / Bn;           // 2

    char* ws = (char*)d_ws;
    _Float16* fh = (_Float16*)ws;
    size_t off = (size_t)M * DD * sizeof(_Float16);
    int* labm = (int*)(ws + off); off += (size_t)M * sizeof(int);
    int* hist = (int*)(ws + off); off += (size_t)NBINS * sizeof(int);
    off = (off + 255) & ~(size_t)255;
    float* EpE = (float*)(ws + off); off += (size_t)NSLICE * M * sizeof(float);
    float* EpP = (float*)(ws + off); off += (size_t)NSLICE * M * sizeof(float);
    float* EcE = (float*)(ws + off); off += (size_t)128 * M * sizeof(float);
    float* EcP = (float*)(ws + off); off += (size_t)128 * M * sizeof(float);

    // zero row partials (EpE+EpP contiguous) + hist + d_out
    const int n4 = (NSLICE * M * 2) / 4;            // 196608 float4
    zero_kernel<<<(n4 + 255) / 256, 256, 0, stream>>>((float4*)EpE, n4, hist,
                                                      (float*)d_out);

    norm_kernel<<<M / 4, 256, 0, stream>>>(feats, labels, fh, labm, hist, M, nrep);

    dim3 grid(M / 512, NSLICE);        // 16 pairs x 48 slices = 768 blocks
    supcon_main<<<grid, 256, 0, stream>>>(fh, labm, EpE, EpP, EcE, EcP, M);

    final_fused<<<M / 256, 256, 0, stream>>>(fh, EpE, EpP, EcE, EcP, labm, hist,
                                             (float*)d_out, M);
}

// Round 20
// 48.853 us; speedup vs baseline: 1.7273x; 1.7273x over previous
//
#include <hip/hip_runtime.h>
#include <math.h>

#define DD 128
#define NSPLIT 24
#define NBINS 512
#define SHIFT 10.0f
#define L2E_T 14.4269504089f   // 10 * log2(e)

#define AS1 __attribute__((address_space(1)))
#define AS3 __attribute__((address_space(3)))

typedef _Float16 f16x8 __attribute__((ext_vector_type(8)));
typedef _Float16 f16x2 __attribute__((ext_vector_type(2)));
typedef float f32x4 __attribute__((ext_vector_type(4)));

// guard-free 2^x: args are in [-29, 0], no denorm/overflow concerns
__device__ __forceinline__ float ex2(float x) {
#if __has_builtin(__builtin_amdgcn_exp2f)
    return __builtin_amdgcn_exp2f(x);
#else
    return exp2f(x);
#endif
}

// ---- tiny zero: hist (512 ints) + d_out; 1 block, ~1us ----
__global__ __launch_bounds__(256)
void zero_kernel(int* __restrict__ hist, float* __restrict__ out)
{
    hist[threadIdx.x] = 0;
    hist[256 + threadIdx.x] = 0;
    if (threadIdx.x == 0) out[0] = 0.f;
}

// ---- normalize rows -> f16, labels, histogram ----
__global__ __launch_bounds__(256)
void norm_kernel(const float* __restrict__ f, const int* __restrict__ labels,
                 _Float16* __restrict__ fh, int* __restrict__ labm,
                 int* __restrict__ hist, int M, int nrep)
{
    int gw = (blockIdx.x * 256 + threadIdx.x) >> 6;   // one wave per row
    int lane = threadIdx.x & 63;
    if (gw >= M) return;
    float2 v = *reinterpret_cast<const float2*>(&f[(size_t)gw * DD + lane * 2]);
    float ss = v.x * v.x + v.y * v.y;
    #pragma unroll
    for (int m = 1; m < 64; m <<= 1) ss += __shfl_xor(ss, m);
    float inv = 1.0f / fmaxf(sqrtf(ss), 1e-12f);
    f16x2 h; h[0] = (_Float16)(v.x * inv); h[1] = (_Float16)(v.y * inv);
    *reinterpret_cast<f16x2*>(&fh[(size_t)gw * DD + lane * 2]) = h;
    if (lane == 0) {
        int lb = labels[gw / nrep];
        labm[gw] = lb;
        if ((gw % nrep) == 0) atomicAdd(&hist[lb], nrep);  // one atomic per sample
    }
}

// ---- main: f16 MFMA, global_load_lds staging, PAIRED subtile phases ----
// Session-best configuration (R17, 49.0us total). 4 waves/block, 64 i-rows
// register-resident (bfr[4][4] = 64 regs), (256,3), 32x24 grid = 3
// blocks/CU single round. j-subtiles staged in 4-subtile batches (16KB)
// into double-buffered LDS via __builtin_amdgcn_global_load_lds (zero
// VGPR cost -- every reg-staged variant spilled). Rule-21 layout: linear
// DMA dest + inverse-swizzled global source + same XOR on ds_read
// (involution) -> 2-way bank = free. Subtiles processed in PAIRS:
// {ds_read af(k); MFMA->accA; ds_read af(k+1); MFMA->accB; EPI(A); EPI(B)}
// -- accA's drain covered by af(k+1) ds_read + MFMA-B, accB's by EPI(A).
// Self-pair included; final kernel subtracts it exactly.
__global__ __launch_bounds__(256, 3)
void supcon_main(const _Float16* __restrict__ fh, const int* __restrict__ labm,
                 float* __restrict__ Epart, float* __restrict__ Ppart,
                 int M, int nsub_total)
{
    __shared__ float4 jbuf[2][1024];   // 2 x (64 rows x 16 chunks of 16B)

    const int tid = threadIdx.x;
    const int lane = tid & 63;
    const int w = tid >> 6;
    const int ibase = blockIdx.x * 256 + w * 64;
    const int rowsel = lane & 15;
    const int grp = lane >> 4;
    const int ksel = grp * 8;      // f16 k-offset within a 32-wide K step

    // register-resident Fi fragments: 4 subtiles x 4 K-steps = 64 regs
    f16x8 bfr[4][4];
    #pragma unroll
    for (int t = 0; t < 4; ++t)
        #pragma unroll
        for (int kk = 0; kk < 4; ++kk)
            bfr[t][kk] = *reinterpret_cast<const f16x8*>(
                &fh[(size_t)(ibase + t * 16 + rowsel) * DD + kk * 32 + ksel]);

    int li[4];
    #pragma unroll
    for (int t = 0; t < 4; ++t) li[t] = labm[ibase + t * 16 + rowsel];

    float esum[4] = {0.f, 0.f, 0.f, 0.f};
    float psum[4] = {0.f, 0.f, 0.f, 0.f};

    // uneven subtile range for this j-split
    const int base = nsub_total / NSPLIT, rem = nsub_total % NSPLIT;
    const int by = blockIdx.y;
    const int s0 = by * base + (by < rem ? by : rem);
    const int send = s0 + base + (by < rem ? 1 : 0);
    const int nsub = send - s0;          // 21 or 22
    const int nb = (nsub + 3) >> 2;      // 4-subtile batches
    const int rowmax = nsub_total * 16 - 1;

    // staging geometry: wave w, instr p covers LDS slots [(p*4+w)*64, +64);
    // slot s holds global chunk (row = s>>4, c = (s&15) ^ ((s>>4)&7)) so the
    // linear DMA write produces the swizzled layout the reader expects.
    int srow[4], scol[4];
    #pragma unroll
    for (int p = 0; p < 4; ++p) {
        int s = (p * 4 + w) * 64 + lane;
        srow[p] = s >> 4;                          // batch-local row 0..63
        scol[p] = ((s & 15) ^ ((s >> 4) & 7)) * 8; // f16 offset of source chunk
    }

#define STAGE(bb, tt) { \
    const int rb = (s0 + (tt) * 4) * 16; \
    _Pragma("unroll") for (int p = 0; p < 4; ++p) { \
        int rr = rb + srow[p]; if (rr > rowmax) rr = rowmax; \
        const _Float16* gsrc = fh + (size_t)rr * DD + scol[p]; \
        __builtin_amdgcn_global_load_lds((const AS1 void*)gsrc, \
            (AS3 void*)&jbuf[bb][(p * 4 + w) * 64], 16, 0, 0); } }

#define LDSAF(bb, k) { \
    _Pragma("unroll") for (int kk = 0; kk < 4; ++kk) { \
        int slot = ((k) * 16 + rowsel) * 16 + ((kk * 4 + grp) ^ (rowsel & 7)); \
        af[kk] = *reinterpret_cast<const f16x8*>(&jbuf[bb][slot]); } }

#define MFMA16(A, c0, c1, c2, c3) { \
    _Pragma("unroll") for (int kk = 0; kk < 4; ++kk) { \
        c0 = __builtin_amdgcn_mfma_f32_16x16x32_f16(A[kk], bfr[0][kk], c0, 0, 0, 0); \
        c1 = __builtin_amdgcn_mfma_f32_16x16x32_f16(A[kk], bfr[1][kk], c1, 0, 0, 0); \
        c2 = __builtin_amdgcn_mfma_f32_16x16x32_f16(A[kk], bfr[2][kk], c2, 0, 0, 0); \
        c3 = __builtin_amdgcn_mfma_f32_16x16x32_f16(A[kk], bfr[3][kk], c3, 0, 0, 0); } }

#define EPI1(t, cc, L) { \
    esum[t] += (ex2(__builtin_fmaf(cc[0], L2E_T, -L2E_T)) \
              + ex2(__builtin_fmaf(cc[1], L2E_T, -L2E_T))) \
             + (ex2(__builtin_fmaf(cc[2], L2E_T, -L2E_T)) \
              + ex2(__builtin_fmaf(cc[3], L2E_T, -L2E_T))); \
    float p0 = (L.x == li[t]) ? cc[0] : 0.f; \
    float p1 = (L.y == li[t]) ? cc[1] : 0.f; \
    float p2 = (L.z == li[t]) ? cc[2] : 0.f; \
    float p3 = (L.w == li[t]) ? cc[3] : 0.f; \
    psum[t] += (p0 + p1) + (p2 + p3); }

#define EPI4(c0, c1, c2, c3, L) { \
    EPI1(0, c0, L); EPI1(1, c1, L); EPI1(2, c2, L); EPI1(3, c3, L); }

// paired phase: two subtiles k0,k1 of batch tt; af reused (16-reg transient)
#define PAIR(bb, tt, k0, k1) { \
    f16x8 af[4]; \
    LDSAF(bb, k0); \
    f32x4 A0 = {0,0,0,0}, A1 = {0,0,0,0}, A2 = {0,0,0,0}, A3 = {0,0,0,0}; \
    MFMA16(af, A0, A1, A2, A3); \
    LDSAF(bb, k1); \
    f32x4 B0 = {0,0,0,0}, B1 = {0,0,0,0}, B2 = {0,0,0,0}, B3 = {0,0,0,0}; \
    MFMA16(af, B0, B1, B2, B3); \
    const int4 lj0 = *reinterpret_cast<const int4*>( \
        &labm[(s0 + (tt) * 4 + (k0)) * 16 + grp * 4]); \
    const int4 lj1 = *reinterpret_cast<const int4*>( \
        &labm[(s0 + (tt) * 4 + (k1)) * 16 + grp * 4]); \
    EPI4(A0, A1, A2, A3, lj0); \
    EPI4(B0, B1, B2, B3, lj1); }

#define SINGLE(bb, tt, k0) { \
    f16x8 af[4]; \
    LDSAF(bb, k0); \
    f32x4 A0 = {0,0,0,0}, A1 = {0,0,0,0}, A2 = {0,0,0,0}, A3 = {0,0,0,0}; \
    MFMA16(af, A0, A1, A2, A3); \
    const int4 lj0 = *reinterpret_cast<const int4*>( \
        &labm[(s0 + (tt) * 4 + (k0)) * 16 + grp * 4]); \
    EPI4(A0, A1, A2, A3, lj0); }

    STAGE(0, 0);
    __syncthreads();                         // drain batch-0 DMA + barrier
    for (int t = 0; t < nb; ++t) {
        if (t + 1 < nb) STAGE((t + 1) & 1, t + 1);   // DMA next batch
        const int nv = (t == nb - 1) ? (nsub - (nb - 1) * 4) : 4;
        if (nv >= 2) PAIR(t & 1, t, 0, 1);
        if (nv == 4) { PAIR(t & 1, t, 2, 3); }
        else if (nv == 3) { SINGLE(t & 1, t, 2); }
        else if (nv == 1) { SINGLE(t & 1, t, 0); }
        __syncthreads();                     // drain DMA + readers done
    }
#undef STAGE
#undef LDSAF
#undef MFMA16
#undef EPI1
#undef EPI4
#undef PAIR
#undef SINGLE

    // fold lane groups (bits 4,5 = different j rows of the same i)
    #pragma unroll
    for (int t = 0; t < 4; ++t) {
        float e = esum[t], p = psum[t];
        e += __shfl_xor(e, 16); e += __shfl_xor(e, 32);
        p += __shfl_xor(p, 16); p += __shfl_xor(p, 32);
        if (lane < 16) {
            size_t o = (size_t)by * M + ibase + t * 16 + lane;
            Epart[o] = e;
            Ppart[o] = p;
        }
    }
}

// ---- per-row loss term: one thread per row, coalesced partial reads,
// block-reduce, one atomic per block ----
__global__ __launch_bounds__(256)
void final_fused(const _Float16* __restrict__ fh, const float* __restrict__ Epart,
                 const float* __restrict__ Ppart, const int* __restrict__ labm,
                 const int* __restrict__ hist, float* __restrict__ out, int M)
{
    __shared__ float red[4];
    const int i = blockIdx.x * 256 + threadIdx.x;   // one row per thread
    float aii = 0.f;
    const f16x8* fr = reinterpret_cast<const f16x8*>(&fh[(size_t)i * DD]);
    #pragma unroll
    for (int k = 0; k < 16; ++k) {
        f16x8 hv = fr[k];
        #pragma unroll
        for (int e = 0; e < 8; ++e) {
            float x = (float)hv[e];
            aii = __builtin_fmaf(x, x, aii);
        }
    }
    float E = 0.f, P = 0.f;
    #pragma unroll
    for (int k = 0; k < NSPLIT; ++k) {
        E += Epart[(size_t)k * M + i];
        P += Ppart[(size_t)k * M + i];
    }
    int lb = labm[i];
    float cnt = (float)(hist[lb] - 1);
    E -= ex2(__builtin_fmaf(aii, L2E_T, -L2E_T));   // drop self exp
    float term = (SHIFT + logf(E)) - SHIFT * (P - aii) / cnt;

    #pragma unroll
    for (int m = 1; m < 64; m <<= 1) term += __shfl_xor(term, m);
    int lane = threadIdx.x & 63, wv = threadIdx.x >> 6;
    if (lane == 0) red[wv] = term;
    __syncthreads();
    if (threadIdx.x == 0)
        atomicAdd(out, (red[0] + red[1] + red[2] + red[3]) / (float)M);
}

extern "C" void kernel_launch(void* const* d_in, const int* in_sizes, int n_in,
                              void* d_out, int out_size, void* d_ws, size_t ws_size,
                              hipStream_t stream)
{
    const float* feats = (const float*)d_in[0];
    const int* labels = (const int*)d_in[1];
    const int Bn = in_sizes[1];
    const int M = in_sizes[0] / DD;    // 8192
    const int nrep = M / Bn;           // 2

    char* ws = (char*)d_ws;
    _Float16* fh = (_Float16*)ws;
    size_t off = (size_t)M * DD * sizeof(_Float16);
    int* labm = (int*)(ws + off); off += (size_t)M * sizeof(int);
    int* hist = (int*)(ws + off); off += (size_t)NBINS * sizeof(int);
    off = (off + 255) & ~(size_t)255;
    float* Epart = (float*)(ws + off); off += (size_t)NSPLIT * M * sizeof(float);
    float* Ppart = (float*)(ws + off); off += (size_t)NSPLIT * M * sizeof(float);

    zero_kernel<<<1, 256, 0, stream>>>(hist, (float*)d_out);

    norm_kernel<<<M / 4, 256, 0, stream>>>(feats, labels, fh, labm, hist, M, nrep);

    const int nsub_total = M / 16;     // 512 j-subtiles split unevenly over 24
    dim3 grid(M / 256, NSPLIT);        // 32 x 24 = 768 blocks (3/CU, 1 round)
    supcon_main<<<grid, 256, 0, stream>>>(fh, labm, Epart, Ppart, M, nsub_total);

    final_fused<<<M / 256, 256, 0, stream>>>(fh, Epart, Ppart, labm, hist,
                                             (float*)d_out, M);
}